// Round 1
// baseline (494.640 us; speedup 1.0000x reference)
//
#include <hip/hip_runtime.h>
#include <cstddef>

// Problem constants (bs=16, T=50, A=3, H=W=76, C=80, stride 8)
#define NB 16
#define NT 50
#define NA 3
#define NH 76
#define NW 76
#define NC 80
#define HWSZ (NH*NW)          // 5776
#define TSTRIDE 16            // floats per target record in ws
#define WS_TGT_OFF 16         // ws[0..5]=loss accums, ws[7]=n_obj, then target records

// scaled anchors = ANCHORS/8, scaled total = TOTAL/8
__constant__ float d_taw[9] = {1.25f,2.0f,4.125f,3.75f,7.75f,7.375f,14.5f,19.5f,46.625f};
__constant__ float d_tah[9] = {1.625f,3.75f,2.875f,7.625f,5.625f,14.875f,11.25f,24.75f,40.75f};
__constant__ float d_saw[3] = {1.25f,2.0f,4.125f};
__constant__ float d_sah[3] = {1.625f,3.75f,2.875f};

__device__ __forceinline__ float safelog(float p) {
    // matches torch/jax BCE clamp at -100
    return p > 0.f ? logf(p) : -100.f;
}
__device__ __forceinline__ float bce(float p, float t) {
    return -(t * safelog(p) + (1.f - t) * safelog(1.f - p));
}
__device__ __forceinline__ float sl1(float p, float t) {
    float d = fabsf(p - t);
    return d < 1.f ? 0.5f * d * d : d - 0.5f;
}
__device__ __forceinline__ float sigmoidf(float z) { return 1.f / (1.f + expf(-z)); }

// ---------------- kernel 1: per-target precompute (one block) ----------------
// target record layout (TSTRIDE floats):
//  0:x1 1:y1 2:x2 3:y2 4:area 5:valid 6:ai_if_write(-1 else) 7:gi 8:gj
//  9:scales 10:tx 11:ty 12:tw 13:th 14:cls
__global__ void k_targets(const float* __restrict__ tg, float* __restrict__ ws) {
    int tid = threadIdx.x;
    if (tid < 16) ws[tid] = 0.f;           // zero loss accumulators (+spare)
    __shared__ int s_nobj;
    if (tid == 0) s_nobj = 0;
    __syncthreads();
    if (tid < NB * NT) {
        const float* tp = tg + (size_t)tid * 5;
        float t0 = tp[0], t1 = tp[1], t2 = tp[2], t3 = tp[3], t4 = tp[4];
        bool valid = (t0 + t1 + t2 + t3 + t4) != 0.f;
        float gx = t1 * NW, gy = t2 * NH, gw = t3 * NW, gh = t4 * NH;
        int gi = (int)gx, gj = (int)gy;    // truncation; gx,gy >= 0
        // best of 9 total anchors: centered boxes -> inter = min(w)*min(h)
        float best = -1.f; int bn = 0;
        #pragma unroll
        for (int n = 0; n < 9; n++) {
            float inter = fminf(gw, d_taw[n]) * fminf(gh, d_tah[n]);
            float iou = inter / (gw * gh + d_taw[n] * d_tah[n] - inter + 1e-16f);
            if (iou > best) { best = iou; bn = n; }   // first-max wins, like argmax
        }
        int ai = (bn < NA) ? bn : -1;
        bool write = valid && (ai >= 0);
        int aic = (ai < 0) ? 0 : ai;
        float* o = ws + WS_TGT_OFF + (size_t)tid * TSTRIDE;
        o[0] = gx - gw * 0.5f;  o[1] = gy - gh * 0.5f;
        o[2] = gx + gw * 0.5f;  o[3] = gy + gh * 0.5f;
        o[4] = (o[2] - o[0]) * (o[3] - o[1]);         // area, same rounding as ref
        o[5] = valid ? 1.f : 0.f;
        o[6] = write ? (float)ai : -1.f;
        o[7] = (float)gi;       o[8] = (float)gj;
        o[9] = 2.f - t3 * t4;
        o[10] = gx - (float)gi; o[11] = gy - (float)gj;
        o[12] = logf(gw / d_saw[aic] + 1e-16f);
        o[13] = logf(gh / d_sah[aic] + 1e-16f);
        o[14] = (float)((int)t0);
        if (valid) atomicAdd(&s_nobj, 1);
    }
    __syncthreads();
    if (tid == 0) ws[7] = (float)s_nobj;
}

// ---------------- kernel 2: per-cell losses ----------------
__global__ __launch_bounds__(256) void k_main(const float* __restrict__ in,
                                              const float* __restrict__ ws,
                                              float* __restrict__ acc) {
    const int b = blockIdx.y / NA;
    const int a = blockIdx.y % NA;
    const int p = blockIdx.x * 256 + threadIdx.x;

    __shared__ float st[NT * TSTRIDE];     // this image's 50 target records (3.2 KB)
    const float* src = ws + WS_TGT_OFF + (size_t)(b * NT) * TSTRIDE;
    for (int k = threadIdx.x; k < NT * TSTRIDE; k += 256) st[k] = src[k];
    __syncthreads();

    float lx = 0.f, ly = 0.f, lw = 0.f, lh = 0.f, lc = 0.f, lcls = 0.f;
    if (p < HWSZ) {
        const int j = p / NW, i = p - j * NW;
        const float* base = in + (size_t)(b * 255 + a * 85) * HWSZ + p;
        float zx = base[0];
        float zy = base[(size_t)1 * HWSZ];
        float zw = base[(size_t)2 * HWSZ];
        float zh = base[(size_t)3 * HWSZ];
        float zc = base[(size_t)4 * HWSZ];
        float x = sigmoidf(zx), y = sigmoidf(zy), conf = sigmoidf(zc);
        // decoded pred box (corner form)
        float pbx = x + (float)i, pby = y + (float)j;
        float pbw = expf(zw) * d_saw[a], pbh = expf(zh) * d_sah[a];
        float px1 = pbx - pbw * 0.5f, px2 = pbx + pbw * 0.5f;
        float py1 = pby - pbh * 0.5f, py2 = pby + pbh * 0.5f;
        float parea = (px2 - px1) * (py2 - py1);

        bool ignore = false;
        int t_last = -1;
        unsigned long long m0 = 0ull; unsigned m1 = 0u;   // tcls bitmask (80 classes)
        const float fa = (float)a, fi = (float)i, fj = (float)j;
        for (int t = 0; t < NT; t++) {
            const float* td = st + t * TSTRIDE;
            if (td[5] != 0.f) {
                float iw = fminf(td[2], px2) - fmaxf(td[0], px1);
                float ih = fminf(td[3], py2) - fmaxf(td[1], py1);
                iw = fmaxf(iw, 0.f); ih = fmaxf(ih, 0.f);
                float inter = iw * ih;
                float iou = inter / (td[4] + parea - inter + 1e-16f);
                if (iou >= 0.5f) ignore = true;
            }
            if (td[6] == fa && td[7] == fi && td[8] == fj) {
                t_last = t;                       // last write wins (scatter order)
                int cls = (int)td[14];
                if (cls < 64) m0 |= 1ull << cls; else m1 |= 1u << (cls - 64);
            }
        }

        if (t_last >= 0) {
            const float* td = st + t_last * TSTRIDE;
            float sc = td[9];
            lx = sc * bce(x, td[10]);
            ly = sc * bce(y, td[11]);
            lw = sc * sl1(zw, td[12]);
            lh = sc * sl1(zh, td[13]);
            lc = -safelog(conf);                  // bce(conf, 1)
            for (int c = 0; c < NC; c++) {
                float z = base[(size_t)(5 + c) * HWSZ];
                float pc = sigmoidf(z);
                float tc = ((c < 64) ? ((m0 >> c) & 1ull) : ((m1 >> (c - 64)) & 1u))
                               ? 1.f : 0.f;
                lcls += bce(pc, tc);
            }
        } else if (!ignore) {
            lc = 0.5f * (-safelog(1.f - conf));   // 0.5 * bce(conf, 0), noobj cell
        }
    }

    // block reduce 6 sums: wave64 shuffle, then one atomic per wave per value
    float v[6] = {lx, ly, lw, lh, lc, lcls};
    #pragma unroll
    for (int k = 0; k < 6; k++) {
        float s = v[k];
        #pragma unroll
        for (int off = 32; off > 0; off >>= 1) s += __shfl_down(s, off);
        if ((threadIdx.x & 63) == 0) atomicAdd(&acc[k], s);
    }
}

// ---------------- kernel 3: finalize ----------------
__global__ void k_final(const float* __restrict__ ws, float* __restrict__ out) {
    float n = ws[7];
    float lx = ws[0] / n, ly = ws[1] / n, lw = ws[2] / n, lh = ws[3] / n;
    float lc = ws[4] / n, lcls = ws[5] / n;
    out[0] = 2.5f * (lx + ly) + 2.5f * (lw + lh) + lc + lcls;
    out[1] = lx; out[2] = ly; out[3] = lw; out[4] = lh; out[5] = lc; out[6] = lcls;
}

extern "C" void kernel_launch(void* const* d_in, const int* in_sizes, int n_in,
                              void* d_out, int out_size, void* d_ws, size_t ws_size,
                              hipStream_t stream) {
    const float* input   = (const float*)d_in[0];   // [16,255,76,76] f32
    const float* targets = (const float*)d_in[1];   // [16,50,5] f32
    float* out = (float*)d_out;                     // 7 f32
    float* ws  = (float*)d_ws;                      // accumulators + target records

    k_targets<<<1, 832, 0, stream>>>(targets, ws);
    dim3 grid((HWSZ + 255) / 256, NB * NA);         // (23, 48)
    k_main<<<grid, 256, 0, stream>>>(input, ws, ws);
    k_final<<<1, 1, 0, stream>>>(ws, out);
}

// Round 2
// 166.894 us; speedup vs baseline: 2.9638x; 2.9638x over previous
//
#include <hip/hip_runtime.h>
#include <cstddef>

// Problem constants (bs=16, T=50, A=3, H=W=76, C=80, stride 8)
#define NB 16
#define NT 50
#define NA 3
#define NH 76
#define NW 76
#define NC 80
#define HWSZ (NH*NW)          // 5776
#define NBLKX 23              // ceil(5776/256)
#define NBLK (NBLKX * NB * NA) // 1104 blocks total

// scaled anchors = ANCHORS/8, scaled total = TOTAL/8
__constant__ float d_taw[9] = {1.25f,2.0f,4.125f,3.75f,7.75f,7.375f,14.5f,19.5f,46.625f};
__constant__ float d_tah[9] = {1.625f,3.75f,2.875f,7.625f,5.625f,14.875f,11.25f,24.75f,40.75f};
__constant__ float d_saw[3] = {1.25f,2.0f,4.125f};
__constant__ float d_sah[3] = {1.625f,3.75f,2.875f};

__device__ __forceinline__ float safelog(float p) {
    return p > 0.f ? logf(p) : -100.f;   // torch/jax BCE clamp
}
__device__ __forceinline__ float bce(float p, float t) {
    return -(t * safelog(p) + (1.f - t) * safelog(1.f - p));
}
__device__ __forceinline__ float sl1(float p, float t) {
    float d = fabsf(p - t);
    return d < 1.f ? 0.5f * d * d : d - 0.5f;
}
__device__ __forceinline__ float sigmoidf(float z) { return 1.f / (1.f + expf(-z)); }

// ---------------- kernel 1: per-cell losses, block partials ----------------
// LDS target record (16 floats):
//   0:x1 1:y1 2:x2 3:y2 4:area(+inf if invalid) 5:key(-1 if no-write)
//   8:scales 9:tx 10:ty 11:tw 12:th 13:cls
__global__ __launch_bounds__(256) void k_main(const float* __restrict__ in,
                                              const float* __restrict__ tg,
                                              float* __restrict__ partials) {
    const int b = blockIdx.y / NA;
    const int a = blockIdx.y % NA;
    const int p = blockIdx.x * 256 + threadIdx.x;

    __shared__ __align__(16) float st[NT][16];   // 3.2 KB
    if (threadIdx.x < NT) {
        const float* tp = tg + ((size_t)b * NT + threadIdx.x) * 5;
        float t0 = tp[0], t1 = tp[1], t2 = tp[2], t3 = tp[3], t4 = tp[4];
        bool valid = (t0 + t1 + t2 + t3 + t4) != 0.f;
        float gx = t1 * NW, gy = t2 * NH, gw = t3 * NW, gh = t4 * NH;
        int gi = (int)gx, gj = (int)gy;          // truncation; gx,gy >= 0
        // best of 9 total anchors (centered boxes -> inter = min(w)*min(h));
        // first-max wins, matching jnp.argmax
        float best = -1.f; int bn = 0;
        #pragma unroll
        for (int n = 0; n < 9; n++) {
            float inter = fminf(gw, d_taw[n]) * fminf(gh, d_tah[n]);
            float iou = inter / (gw * gh + d_taw[n] * d_tah[n] - inter + 1e-16f);
            if (iou > best) { best = iou; bn = n; }
        }
        int ai = (bn < NA) ? bn : -1;
        bool write = valid && (ai >= 0);
        int aic = (ai < 0) ? 0 : ai;
        float x1 = gx - gw * 0.5f, y1 = gy - gh * 0.5f;
        float x2 = gx + gw * 0.5f, y2 = gy + gh * 0.5f;
        float* o = st[threadIdx.x];
        o[0] = x1; o[1] = y1; o[2] = x2; o[3] = y2;
        o[4] = valid ? (x2 - x1) * (y2 - y1) : __builtin_inff();
        o[5] = write ? (float)(ai * HWSZ + gj * NW + gi) : -1.f;  // exact in fp32 (<2^24)
        o[8] = 2.f - t3 * t4;
        o[9] = gx - (float)gi; o[10] = gy - (float)gj;
        o[11] = logf(gw / d_saw[aic] + 1e-16f);
        o[12] = logf(gh / d_sah[aic] + 1e-16f);
        o[13] = (float)((int)t0);
    }
    __syncthreads();

    float lx = 0.f, ly = 0.f, lw = 0.f, lh = 0.f, lc = 0.f, lcls = 0.f;
    if (p < HWSZ) {
        const int j = p / NW, i = p - j * NW;
        const float* base = in + (size_t)(b * 255 + a * 85) * HWSZ + p;
        float zx = base[0];
        float zy = base[(size_t)1 * HWSZ];
        float zw = base[(size_t)2 * HWSZ];
        float zh = base[(size_t)3 * HWSZ];
        float zc = base[(size_t)4 * HWSZ];
        float x = sigmoidf(zx), y = sigmoidf(zy), conf = sigmoidf(zc);
        float pbx = x + (float)i, pby = y + (float)j;
        float pbw = expf(zw) * d_saw[a], pbh = expf(zh) * d_sah[a];
        float px1 = pbx - pbw * 0.5f, px2 = pbx + pbw * 0.5f;
        float py1 = pby - pbh * 0.5f, py2 = pby + pbh * 0.5f;
        float parea = (px2 - px1) * (py2 - py1);
        const float ck = (float)(a * HWSZ + p);  // cell key

        bool ignore = false;
        int t_last = -1;
        unsigned long long m0 = 0ull; unsigned m1 = 0u;   // tcls bitmask (80 classes)
        for (int t = 0; t < NT; t++) {
            const float4 h0 = *(const float4*)&st[t][0];  // x1,y1,x2,y2 (LDS broadcast)
            const float area = st[t][4], key = st[t][5];
            float iw = fminf(h0.z, px2) - fmaxf(h0.x, px1);
            float ih = fminf(h0.w, py2) - fmaxf(h0.y, py1);
            iw = fmaxf(iw, 0.f); ih = fmaxf(ih, 0.f);
            float inter = iw * ih;
            // iou >= 0.5  <=>  3*inter >= area + parea  (denominator > 0)
            if (3.f * inter >= area + parea) ignore = true;
            if (key == ck) {
                t_last = t;                       // last scatter wins
                int cls = (int)st[t][13];
                if (cls < 64) m0 |= 1ull << cls; else m1 |= 1u << (cls - 64);
            }
        }

        if (t_last >= 0) {
            const float* td = st[t_last];
            float sc = td[8];
            lx = sc * bce(x, td[9]);
            ly = sc * bce(y, td[10]);
            lw = sc * sl1(zw, td[11]);
            lh = sc * sl1(zh, td[12]);
            lc = -safelog(conf);                  // bce(conf, 1)
            for (int c = 0; c < NC; c++) {
                float z = base[(size_t)(5 + c) * HWSZ];
                float pc = sigmoidf(z);
                float tc = ((c < 64) ? ((m0 >> c) & 1ull) : ((m1 >> (c - 64)) & 1u))
                               ? 1.f : 0.f;
                lcls += bce(pc, tc);
            }
        } else if (!ignore) {
            lc = 0.5f * (-safelog(1.f - conf));   // 0.5 * bce(conf, 0)
        }
    }

    // block reduction: wave64 shuffle -> LDS -> 6 plain stores (NO atomics)
    float v[6] = {lx, ly, lw, lh, lc, lcls};
    __shared__ float red[4][6];
    const int wid = threadIdx.x >> 6, lane = threadIdx.x & 63;
    #pragma unroll
    for (int k = 0; k < 6; k++) {
        float s = v[k];
        #pragma unroll
        for (int off = 32; off > 0; off >>= 1) s += __shfl_down(s, off);
        if (lane == 0) red[wid][k] = s;
    }
    __syncthreads();
    if (threadIdx.x < 6) {
        const int blk = blockIdx.y * NBLKX + blockIdx.x;
        partials[(size_t)blk * 8 + threadIdx.x] =
            red[0][threadIdx.x] + red[1][threadIdx.x] + red[2][threadIdx.x] + red[3][threadIdx.x];
    }
}

// ---------------- kernel 2: reduce partials + n_obj + finalize ----------------
__global__ __launch_bounds__(512) void k_final(const float* __restrict__ tg,
                                               const float* __restrict__ partials,
                                               float* __restrict__ out) {
    const int wid = threadIdx.x >> 6, lane = threadIdx.x & 63;
    __shared__ float rs[8];
    if (wid < 6) {
        float s = 0.f;
        for (int i = lane; i < NBLK; i += 64) s += partials[(size_t)i * 8 + wid];
        #pragma unroll
        for (int off = 32; off > 0; off >>= 1) s += __shfl_down(s, off);
        if (lane == 0) rs[wid] = s;
    } else if (wid == 6) {
        int c = 0;
        for (int i = lane; i < NB * NT; i += 64) {
            const float* tp = tg + (size_t)i * 5;
            if ((tp[0] + tp[1] + tp[2] + tp[3] + tp[4]) != 0.f) c++;
        }
        #pragma unroll
        for (int off = 32; off > 0; off >>= 1) c += __shfl_down(c, off);
        if (lane == 0) rs[6] = (float)c;
    }
    __syncthreads();
    if (threadIdx.x == 0) {
        float n = rs[6];
        float lx = rs[0] / n, ly = rs[1] / n, lw = rs[2] / n, lh = rs[3] / n;
        float lc = rs[4] / n, lcls = rs[5] / n;
        out[0] = 2.5f * (lx + ly) + 2.5f * (lw + lh) + lc + lcls;
        out[1] = lx; out[2] = ly; out[3] = lw; out[4] = lh; out[5] = lc; out[6] = lcls;
    }
}

extern "C" void kernel_launch(void* const* d_in, const int* in_sizes, int n_in,
                              void* d_out, int out_size, void* d_ws, size_t ws_size,
                              hipStream_t stream) {
    const float* input   = (const float*)d_in[0];   // [16,255,76,76] f32
    const float* targets = (const float*)d_in[1];   // [16,50,5] f32
    float* out = (float*)d_out;                     // 7 f32
    float* ws  = (float*)d_ws;                      // block partials: NBLK*8 floats

    dim3 grid(NBLKX, NB * NA);                      // (23, 48)
    k_main<<<grid, 256, 0, stream>>>(input, targets, ws);
    k_final<<<1, 512, 0, stream>>>(targets, ws, out);
}